// Round 5
// baseline (121.171 us; speedup 1.0000x reference)
//
#include <hip/hip_runtime.h>
#include <math.h>

#define NPTS 4096
#define CDIM 512
#define NROWS 16384
#define NTILES 136   // 16*17/2 tiles of 256 per batch
#define FLTMAX 3.402823466e+38f

typedef _Float16 half_t;
typedef _Float16 half8 __attribute__((ext_vector_type(8)));
typedef float f32x4 __attribute__((ext_vector_type(4)));

__device__ inline void gl_lds16(const void* g, void* l) {
    __builtin_amdgcn_global_load_lds(
        (const __attribute__((address_space(1))) uint32_t*)g,
        (__attribute__((address_space(3))) uint32_t*)l, 16, 0, 0);
}

// ============================================================================
// Path A: prep -> fcm_sym (256x256 triangular tiles, both-side fold) -> combine
// Global f16 image: row stride 1024 B; 8 Kblocks of 64 ch (128 B); 16B slot s
// stored at s^(row&7) (pre-baked LDS swizzle, linear global_load_lds dest).
// ============================================================================

__global__ __launch_bounds__(256) void prep_kernel(const float* __restrict__ x,
                                                   half_t* __restrict__ hi,
                                                   float* __restrict__ sq) {
    const int wv = threadIdx.x >> 6, l = threadIdx.x & 63;
    const int row = blockIdx.x * 4 + wv;
    const float* f = x + (size_t)row * CDIM;
    float4 v0 = *(const float4*)(f + l * 8);
    float4 v1 = *(const float4*)(f + l * 8 + 4);
    float xs[8] = {v0.x, v0.y, v0.z, v0.w, v1.x, v1.y, v1.z, v1.w};
    half8 h;
    float s = 0.0f;
    #pragma unroll
    for (int i = 0; i < 8; ++i) {
        float v = xs[i];
        s = fmaf(v, v, s);
        h[i] = (half_t)v;
    }
    #pragma unroll
    for (int o = 32; o > 0; o >>= 1) s += __shfl_xor(s, o);
    const int kb = l >> 3;
    const int pos = (l & 7) ^ (row & 7);
    *(half8*)(hi + (size_t)row * CDIM + kb * 64 + pos * 8) = h;
    if (l == 0) sq[row] = s;
}

// One block per triangular 256x256 tile (I,J), J>=I, per batch. 8 waves (2x4),
// each 128x64 output. BK=64, double-buffered LDS via global_load_lds.
// Row-side fold (rows of I over 64-col sections of J) -> slot 4J+wn.
// Col-side fold (rows of J over 64-row halves of I; skip if I==J)
//   -> slot 4I+2*wm+h. part layout: [slot][row] float4 (m0,m1,m2,max), d^2.
__global__ __launch_bounds__(512, 2) void fcm_sym(const half_t* __restrict__ hi,
                                                  const float* __restrict__ sq,
                                                  float4* __restrict__ part4) {
    __shared__ __align__(16) char smem[2][2][32768];
    const int tid = threadIdx.x, wv = tid >> 6, l = tid & 63;
    const int wm = wv >> 2, wn = wv & 3;
    // XCD-aware bijective swizzle: 544 blocks = 8 XCDs x 68
    const int bid = blockIdx.x;
    const int tl = (bid & 7) * 68 + (bid >> 3);
    const int batch = tl / NTILES;
    const int t = tl - batch * NTILES;
    int I = 0;
    while ((16 * (I + 1) - ((I + 1) * I) / 2) <= t) ++I;
    const int J = I + (t - (16 * I - (I * (I - 1)) / 2));
    const int r0 = (batch << 12) + I * 256;
    const int c0 = (batch << 12) + J * 256;
    const char* base = (const char*)hi;

    // fragment LDS byte offsets: rowa&7 == l&7 for all fragments
    const int s0 = (((l >> 4) + 0) ^ (l & 7)) * 16;
    const int s1 = (((l >> 4) + 4) ^ (l & 7)) * 16;
    const int abase = (wm * 128 + (l & 15)) * 128;
    const int bbase = (wn * 64 + (l & 15)) * 128;

    // stage addressing: db(i) = i*8192 + wv*1024 + l*16
    const int srb = wv * 8 + (l >> 3);        // srow(i) = i*64 + srb
    const int sin = (l & 7) * 16;

#define STAGE(buf, ksv) do {                                                   \
        _Pragma("unroll")                                                      \
        for (int i_ = 0; i_ < 4; ++i_) {                                       \
            const int db_ = i_ * 8192 + wv * 1024;                             \
            const int sr_ = i_ * 64 + srb;                                     \
            gl_lds16(base + (size_t)(r0 + sr_) * 1024 + (ksv) * 128 + sin,     \
                     &smem[buf][0][db_]);                                      \
            gl_lds16(base + (size_t)(c0 + sr_) * 1024 + (ksv) * 128 + sin,     \
                     &smem[buf][1][db_]);                                      \
        } } while (0)

    f32x4 acc[8][4];
    #pragma unroll
    for (int mi = 0; mi < 8; ++mi)
        #pragma unroll
        for (int ni = 0; ni < 4; ++ni)
            #pragma unroll
            for (int j = 0; j < 4; ++j) acc[mi][ni][j] = 0.0f;

    STAGE(0, 0);
    __syncthreads();
    #pragma unroll
    for (int ks = 0; ks < 8; ++ks) {
        const int cur = ks & 1;
        if (ks < 7) STAGE(cur ^ 1, ks + 1);
        #pragma unroll
        for (int kc = 0; kc < 2; ++kc) {
            const int sl = kc ? s1 : s0;
            half8 af[8], bf[4];
            #pragma unroll
            for (int mi = 0; mi < 8; ++mi)
                af[mi] = *(const half8*)&smem[cur][0][abase + mi * 2048 + sl];
            #pragma unroll
            for (int ni = 0; ni < 4; ++ni)
                bf[ni] = *(const half8*)&smem[cur][1][bbase + ni * 2048 + sl];
            #pragma unroll
            for (int mi = 0; mi < 8; ++mi)
                #pragma unroll
                for (int ni = 0; ni < 4; ++ni)
                    acc[mi][ni] = __builtin_amdgcn_mfma_f32_16x16x32_f16(
                        af[mi], bf[ni], acc[mi][ni], 0, 0, 0);
        }
        __syncthreads();
    }
#undef STAGE

    // epilogue sq values
    float sr[32];
    #pragma unroll
    for (int mi = 0; mi < 8; ++mi)
        #pragma unroll
        for (int j = 0; j < 4; ++j)
            sr[mi * 4 + j] = sq[r0 + wm * 128 + mi * 16 + (l >> 4) * 4 + j];
    float scn[4];
    #pragma unroll
    for (int ni = 0; ni < 4; ++ni)
        scn[ni] = sq[c0 + wn * 64 + ni * 16 + (l & 15)];

    // ---- row-side fold, one mi at a time (keeps register pressure low) ----
    #pragma unroll
    for (int mi = 0; mi < 8; ++mi) {
        float st0[4], st1[4], st2[4], stx[4];
        #pragma unroll
        for (int j = 0; j < 4; ++j) {
            st0[j] = FLTMAX; st1[j] = FLTMAX; st2[j] = FLTMAX; stx[j] = 0.0f;
        }
        #pragma unroll
        for (int ni = 0; ni < 4; ++ni) {
            float sc = scn[ni];
            #pragma unroll
            for (int j = 0; j < 4; ++j) {
                float d2v = fmaf(-2.0f, acc[mi][ni][j], sr[mi * 4 + j] + sc);
                float lo0 = fminf(st0[j], d2v), hi0 = fmaxf(st0[j], d2v);
                st0[j] = lo0;
                float lo1 = fminf(st1[j], hi0), hi1 = fmaxf(st1[j], hi0);
                st1[j] = lo1;
                st2[j] = fminf(st2[j], hi1);
                stx[j] = fmaxf(stx[j], d2v);
            }
        }
        #pragma unroll
        for (int s = 1; s < 16; s <<= 1) {
            #pragma unroll
            for (int j = 0; j < 4; ++j) {
                float b0 = __shfl_xor(st0[j], s);
                float b1 = __shfl_xor(st1[j], s);
                float b2 = __shfl_xor(st2[j], s);
                float bm = __shfl_xor(stx[j], s);
                float n0 = fminf(st0[j], b0);
                float n1 = fminf(fmaxf(st0[j], b0), fminf(st1[j], b1));
                float n2 = fminf(fminf(st2[j], b2),
                                 fminf(fmaxf(st0[j], b1), fmaxf(st1[j], b0)));
                st0[j] = n0; st1[j] = n1; st2[j] = n2; stx[j] = fmaxf(stx[j], bm);
            }
        }
        if ((l & 15) == 0) {
            const int g = l >> 4;
            #pragma unroll
            for (int j = 0; j < 4; ++j) {
                int row = r0 + wm * 128 + mi * 16 + g * 4 + j;
                part4[(size_t)(4 * J + wn) * NROWS + row] =
                    make_float4(st0[j], st1[j], st2[j], stx[j]);
            }
        }
    }

    // ---- col-side fold: rows of J over 64-row halves of I ----
    if (J > I) {
        #pragma unroll
        for (int h = 0; h < 2; ++h) {
            #pragma unroll
            for (int ni = 0; ni < 4; ++ni) {
                float cs0 = FLTMAX, cs1 = FLTMAX, cs2 = FLTMAX, csx = 0.0f;
                float sc = scn[ni];
                #pragma unroll
                for (int mi = h * 4; mi < h * 4 + 4; ++mi)
                    #pragma unroll
                    for (int j = 0; j < 4; ++j) {
                        float d2v = fmaf(-2.0f, acc[mi][ni][j], sr[mi * 4 + j] + sc);
                        float lo0 = fminf(cs0, d2v), hi0 = fmaxf(cs0, d2v);
                        cs0 = lo0;
                        float lo1 = fminf(cs1, hi0), hi1 = fmaxf(cs1, hi0);
                        cs1 = lo1;
                        cs2 = fminf(cs2, hi1);
                        csx = fmaxf(csx, d2v);
                    }
                #pragma unroll
                for (int s = 16; s < 64; s <<= 1) {
                    float b0 = __shfl_xor(cs0, s);
                    float b1 = __shfl_xor(cs1, s);
                    float b2 = __shfl_xor(cs2, s);
                    float bm = __shfl_xor(csx, s);
                    float n0 = fminf(cs0, b0);
                    float n1 = fminf(fmaxf(cs0, b0), fminf(cs1, b1));
                    float n2 = fminf(fminf(cs2, b2),
                                     fminf(fmaxf(cs0, b1), fmaxf(cs1, b0)));
                    cs0 = n0; cs1 = n1; cs2 = n2; csx = fmaxf(csx, bm);
                }
                if (l < 16) {
                    int colr = c0 + wn * 64 + ni * 16 + l;
                    part4[(size_t)(4 * I + 2 * wm + h) * NROWS + colr] =
                        make_float4(cs0, cs1, cs2, csx);
                }
            }
        }
    }
}

// combine: fold all 64 slots per row (each written exactly once), sqrt + pred.
__global__ __launch_bounds__(256) void combine_kernel(const float4* __restrict__ part4,
                                                      float* __restrict__ out) {
    const int row = blockIdx.x * 256 + threadIdx.x;
    float m0 = FLTMAX, m1 = FLTMAX, m2 = FLTMAX, mx = 0.0f;
    for (int s = 0; s < 64; ++s) {
        float4 t = part4[(size_t)s * NROWS + row];
        float n0 = fminf(m0, t.x);
        float n1 = fminf(fmaxf(m0, t.x), fminf(m1, t.y));
        float n2 = fminf(fminf(m2, t.z), fminf(fmaxf(m0, t.y), fmaxf(m1, t.x)));
        m0 = n0; m1 = n1; m2 = n2; mx = fmaxf(mx, t.w);
    }
    float d1 = sqrtf(fmaxf(m1, 0.0f) + 1e-12f);
    float d2 = sqrtf(fmaxf(m2, 0.0f) + 1e-12f);
    float dm = sqrtf(fmaxf(mx, 0.0f) + 1e-12f);
    out[row] = (d1 / d2 < 0.6f) ? 2.0f / (1.0f + expf(d1))
                                : 2.0f / (1.0f + 2.0f * expf(dm));
}

// ============================================================================
// Path B (fallback, fp32 VALU) if ws too small
// ============================================================================

__global__ __launch_bounds__(256) void sq_kernel(const float* __restrict__ x,
                                                 float* __restrict__ sq) {
    int wid = threadIdx.x >> 6;
    int lane = threadIdx.x & 63;
    int row = blockIdx.x * 4 + wid;
    const float* f = x + (size_t)row * CDIM;
    float4 v0 = *(const float4*)(f + lane * 8);
    float4 v1 = *(const float4*)(f + lane * 8 + 4);
    float s = v0.x*v0.x + v0.y*v0.y + v0.z*v0.z + v0.w*v0.w
            + v1.x*v1.x + v1.y*v1.y + v1.z*v1.z + v1.w*v1.w;
    #pragma unroll
    for (int o = 32; o > 0; o >>= 1) s += __shfl_xor(s, o);
    if (lane == 0) sq[row] = s;
}

__global__ __launch_bounds__(256, 2) void fcm_kernel(const float* __restrict__ x,
                                                     const float* __restrict__ sq,
                                                     float* __restrict__ out) {
    __shared__ __align__(16) float a_s[32][36];
    __shared__ __align__(16) float b_s[32][260];
    const int tid = threadIdx.x;
    const int ty = tid >> 6;
    const int tx = tid & 63;
    const int brow = blockIdx.x * 32;
    const int batch = brow >> 12;
    const int irow = brow & (NPTS - 1);
    const float* f = x + (size_t)batch * NPTS * CDIM;
    const float* sqb = sq + batch * NPTS;

    float srr[8];
    #pragma unroll
    for (int r = 0; r < 8; ++r) srr[r] = sqb[irow + ty * 8 + r];
    float m0[8], m1[8], m2[8], mx[8];
    #pragma unroll
    for (int r = 0; r < 8; ++r) {
        m0[r] = FLTMAX; m1[r] = FLTMAX; m2[r] = FLTMAX; mx[r] = 0.0f;
    }
    for (int ct = 0; ct < NPTS / 256; ++ct) {
        const int cbase = ct * 256;
        float acc[8][4];
        #pragma unroll
        for (int r = 0; r < 8; ++r)
            #pragma unroll
            for (int q = 0; q < 4; ++q) acc[r][q] = 0.0f;
        for (int kc = 0; kc < CDIM; kc += 32) {
            {
                int row = tid >> 3, l8 = tid & 7;
                float4 v = *(const float4*)(f + (size_t)(irow + row) * CDIM + kc + l8 * 4);
                a_s[l8 * 4 + 0][row] = v.x; a_s[l8 * 4 + 1][row] = v.y;
                a_s[l8 * 4 + 2][row] = v.z; a_s[l8 * 4 + 3][row] = v.w;
            }
            {
                int colb = tid >> 2, l4 = tid & 3;
                #pragma unroll
                for (int it = 0; it < 4; ++it) {
                    int col = colb + 64 * it;
                    const float* p = f + (size_t)(cbase + col) * CDIM + kc + l4 * 8;
                    float4 v0 = *(const float4*)p;
                    float4 v1 = *(const float4*)(p + 4);
                    b_s[l4 * 8 + 0][col] = v0.x; b_s[l4 * 8 + 1][col] = v0.y;
                    b_s[l4 * 8 + 2][col] = v0.z; b_s[l4 * 8 + 3][col] = v0.w;
                    b_s[l4 * 8 + 4][col] = v1.x; b_s[l4 * 8 + 5][col] = v1.y;
                    b_s[l4 * 8 + 6][col] = v1.z; b_s[l4 * 8 + 7][col] = v1.w;
                }
            }
            __syncthreads();
            #pragma unroll
            for (int k = 0; k < 32; ++k) {
                float a0[8], b0[4];
                *(float4*)&a0[0] = *(const float4*)&a_s[k][ty * 8];
                *(float4*)&a0[4] = *(const float4*)&a_s[k][ty * 8 + 4];
                *(float4*)&b0[0] = *(const float4*)&b_s[k][tx * 4];
                #pragma unroll
                for (int r = 0; r < 8; ++r)
                    #pragma unroll
                    for (int q = 0; q < 4; ++q)
                        acc[r][q] = fmaf(a0[r], b0[q], acc[r][q]);
            }
            __syncthreads();
        }
        #pragma unroll
        for (int q = 0; q < 4; ++q) {
            float sc = sqb[cbase + tx * 4 + q];
            #pragma unroll
            for (int r = 0; r < 8; ++r) {
                float d2v = fmaf(-2.0f, acc[r][q], srr[r] + sc);
                d2v = fmaxf(d2v, 0.0f);
                float d = sqrtf(d2v + 1e-12f);
                float lo = fminf(m0[r], d), hi = fmaxf(m0[r], d);
                m0[r] = lo;
                float lo1 = fminf(m1[r], hi), hi1 = fmaxf(m1[r], hi);
                m1[r] = lo1;
                m2[r] = fminf(m2[r], hi1);
                mx[r] = fmaxf(mx[r], d);
            }
        }
    }
    #pragma unroll
    for (int s = 1; s < 64; s <<= 1) {
        #pragma unroll
        for (int r = 0; r < 8; ++r) {
            float b0v = __shfl_xor(m0[r], s);
            float b1v = __shfl_xor(m1[r], s);
            float b2v = __shfl_xor(m2[r], s);
            float bmv = __shfl_xor(mx[r], s);
            float n0 = fminf(m0[r], b0v);
            float n1 = fminf(fmaxf(m0[r], b0v), fminf(m1[r], b1v));
            float n2 = fminf(fminf(m2[r], b2v),
                             fminf(fmaxf(m0[r], b1v), fmaxf(m1[r], b0v)));
            m0[r] = n0; m1[r] = n1; m2[r] = n2; mx[r] = fmaxf(mx[r], bmv);
        }
    }
    if (tx == 0) {
        #pragma unroll
        for (int r = 0; r < 8; ++r) {
            int grow = brow + ty * 8 + r;
            float d1 = m1[r], d2nd = m2[r], dmaxv = mx[r];
            float pred = (d1 / d2nd < 0.6f) ? 2.0f / (1.0f + expf(d1))
                                            : 2.0f / (1.0f + 2.0f * expf(dmaxv));
            out[grow] = pred;
        }
    }
}

extern "C" void kernel_launch(void* const* d_in, const int* in_sizes, int n_in,
                              void* d_out, int out_size, void* d_ws, size_t ws_size,
                              hipStream_t stream) {
    const float* x = (const float*)d_in[0];
    float* out = (float*)d_out;

    const size_t plane = (size_t)NROWS * CDIM * sizeof(half_t);      // 16 MB
    const size_t partb = (size_t)64 * NROWS * sizeof(float4);        // 16 MB
    const size_t need = plane + NROWS * sizeof(float) + partb;

    if (ws_size >= need) {
        half_t* hi = (half_t*)d_ws;
        float* sq = (float*)((char*)d_ws + plane);
        float4* part4 = (float4*)((char*)d_ws + plane + NROWS * sizeof(float));
        prep_kernel<<<dim3(NROWS / 4), dim3(256), 0, stream>>>(x, hi, sq);
        fcm_sym<<<dim3(4 * NTILES), dim3(512), 0, stream>>>(hi, sq, part4);
        combine_kernel<<<dim3(NROWS / 256), dim3(256), 0, stream>>>(part4, out);
    } else {
        float* sqw = (float*)d_ws;
        sq_kernel<<<dim3(4096), dim3(256), 0, stream>>>(x, sqw);
        fcm_kernel<<<dim3(512), dim3(256), 0, stream>>>(x, sqw, out);
    }
}

// Round 6
// 101.628 us; speedup vs baseline: 1.1923x; 1.1923x over previous
//
#include <hip/hip_runtime.h>
#include <math.h>

#define NPTS 4096
#define CDIM 512
#define NROWS 16384
#define NTILES 528   // 32*33/2 tri-tiles of 128 per batch
#define FLTMAX 3.402823466e+38f

typedef _Float16 half_t;
typedef _Float16 half8 __attribute__((ext_vector_type(8)));
typedef float f32x4 __attribute__((ext_vector_type(4)));

__device__ inline void gl_lds16(const void* g, void* l) {
    __builtin_amdgcn_global_load_lds(
        (const __attribute__((address_space(1))) uint32_t*)g,
        (__attribute__((address_space(3))) uint32_t*)l, 16, 0, 0);
}

__device__ __forceinline__ int tri_start(int i) { return 32 * i - (i * (i - 1)) / 2; }

// ============================================================================
// Path A: prep -> fcm_sym (128x128 tri tiles, ring-4 counted-vmcnt pipeline)
// Global f16 image: row stride 1024 B; 8 Kblocks of 64 ch (128 B); 16B slot s
// of each Kblock stored at position s^(row&7).
// ============================================================================

__global__ __launch_bounds__(256) void prep_kernel(const float* __restrict__ x,
                                                   half_t* __restrict__ hi,
                                                   float* __restrict__ sq) {
    const int wv = threadIdx.x >> 6, l = threadIdx.x & 63;
    const int row = blockIdx.x * 4 + wv;
    const float* f = x + (size_t)row * CDIM;
    float4 v0 = *(const float4*)(f + l * 8);
    float4 v1 = *(const float4*)(f + l * 8 + 4);
    float xs[8] = {v0.x, v0.y, v0.z, v0.w, v1.x, v1.y, v1.z, v1.w};
    half8 h;
    float s = 0.0f;
    #pragma unroll
    for (int i = 0; i < 8; ++i) {
        float v = xs[i];
        s = fmaf(v, v, s);
        h[i] = (half_t)v;
    }
    #pragma unroll
    for (int o = 32; o > 0; o >>= 1) s += __shfl_xor(s, o);
    const int kb = l >> 3;
    const int pos = (l & 7) ^ (row & 7);
    *(half8*)(hi + (size_t)row * CDIM + kb * 64 + pos * 8) = h;
    if (l == 0) sq[row] = s;
}

// One block per triangular 128x128 tile (I,J), J>=I, per batch. 4 waves (2x2,
// 64x64 out each). BK=32, 16 K-steps, 4-buffer LDS ring, depth-2 prefetch,
// counted vmcnt(4) at barriers (vmcnt(0) only at the final peel).
// LDS buffer layout per ring slot: A[128 rows][4 slots x 16B], slot for
// ch-chunk c stored at c ^ ((row>>2)&3); B likewise at +8192.
__global__ __launch_bounds__(256, 2) void fcm_sym(const half_t* __restrict__ hi,
                                                  const float* __restrict__ sq,
                                                  float4* __restrict__ part4) {
    __shared__ __align__(16) char smem[4][16384];
    const int tid = threadIdx.x, wv = tid >> 6, l = tid & 63;
    const int wm = wv >> 1, wn = wv & 1;
    const int bid = blockIdx.x;
    const int batch = bid / NTILES;
    const int t = bid - batch * NTILES;
    int I = (int)((65.0f - sqrtf(4225.0f - 8.0f * (float)t)) * 0.5f);
    while (tri_start(I + 1) <= t) ++I;
    while (tri_start(I) > t) --I;
    const int J = I + (t - tri_start(I));
    const int r0 = (batch << 12) + I * 128;
    const int c0 = (batch << 12) + J * 128;
    const char* base = (const char*)hi;

    // staging source pointers (per wave slice; parity = K-step & 1)
    const char* aP[2][2];
    const char* bP[2][2];
    #pragma unroll
    for (int i = 0; i < 2; ++i) {
        int row = wv * 32 + i * 16 + (l >> 2);
        int r7 = row & 7;
        int c = (l & 3) ^ ((row >> 2) & 3);
        aP[i][0] = base + (size_t)(r0 + row) * 1024 + ((c ^ r7) << 4);
        aP[i][1] = base + (size_t)(r0 + row) * 1024 + (((c | 4) ^ r7) << 4);
        bP[i][0] = base + (size_t)(c0 + row) * 1024 + ((c ^ r7) << 4);
        bP[i][1] = base + (size_t)(c0 + row) * 1024 + (((c | 4) ^ r7) << 4);
    }

    // fragment read offsets (lane-constant slot swizzle)
    const int sA = ((l >> 4) ^ ((l >> 2) & 3)) << 4;
    int afo[4], bfo[4];
    #pragma unroll
    for (int q = 0; q < 4; ++q) {
        afo[q] = (wm * 64 + q * 16 + (l & 15)) * 64 + sA;
        bfo[q] = 8192 + (wn * 64 + q * 16 + (l & 15)) * 64 + sA;
    }

#define STAGE(t_) do {                                                        \
        const int rg_ = (t_) & 3, par_ = (t_) & 1;                            \
        const int ko_ = ((t_) >> 1) * 128;                                    \
        gl_lds16(aP[0][par_] + ko_, &smem[rg_][wv * 2048]);                   \
        gl_lds16(aP[1][par_] + ko_, &smem[rg_][wv * 2048 + 1024]);            \
        gl_lds16(bP[0][par_] + ko_, &smem[rg_][8192 + wv * 2048]);            \
        gl_lds16(bP[1][par_] + ko_, &smem[rg_][8192 + wv * 2048 + 1024]);     \
    } while (0)

    f32x4 acc[4][4];
    #pragma unroll
    for (int mi = 0; mi < 4; ++mi)
        #pragma unroll
        for (int ni = 0; ni < 4; ++ni)
            #pragma unroll
            for (int j = 0; j < 4; ++j) acc[mi][ni][j] = 0.0f;

    // prologue: buffers 0 and 1 in flight; wait buf0 only
    STAGE(0);
    STAGE(1);
    asm volatile("s_waitcnt vmcnt(4)" ::: "memory");
    __builtin_amdgcn_s_barrier();

    #pragma unroll
    for (int ks = 0; ks < 16; ++ks) {
        const int rg = ks & 3;
        half8 af[4], bf[4];
        #pragma unroll
        for (int q = 0; q < 4; ++q) {
            af[q] = *(const half8*)&smem[rg][afo[q]];
            bf[q] = *(const half8*)&smem[rg][bfo[q]];
        }
        if (ks < 14) STAGE(ks + 2);
        __builtin_amdgcn_s_setprio(1);
        #pragma unroll
        for (int mi = 0; mi < 4; ++mi)
            #pragma unroll
            for (int ni = 0; ni < 4; ++ni)
                acc[mi][ni] = __builtin_amdgcn_mfma_f32_16x16x32_f16(
                    af[mi], bf[ni], acc[mi][ni], 0, 0, 0);
        __builtin_amdgcn_s_setprio(0);
        if (ks < 15) {
            if (ks < 14) asm volatile("s_waitcnt vmcnt(4)" ::: "memory");
            else         asm volatile("s_waitcnt vmcnt(0)" ::: "memory");
            __builtin_amdgcn_s_barrier();
        }
    }
#undef STAGE

    // epilogue sq values
    float sr[16];
    #pragma unroll
    for (int mi = 0; mi < 4; ++mi)
        #pragma unroll
        for (int j = 0; j < 4; ++j)
            sr[mi * 4 + j] = sq[r0 + wm * 64 + mi * 16 + (l >> 4) * 4 + j];
    float scn[4];
    #pragma unroll
    for (int ni = 0; ni < 4; ++ni)
        scn[ni] = sq[c0 + wn * 64 + ni * 16 + (l & 15)];

    // ---- row-side fold: rows of I over this tile's 128 cols (d^2 domain) ----
    float st0[16], st1[16], st2[16], stx[16];
    #pragma unroll
    for (int i = 0; i < 16; ++i) {
        st0[i] = FLTMAX; st1[i] = FLTMAX; st2[i] = FLTMAX; stx[i] = 0.0f;
    }
    #pragma unroll
    for (int ni = 0; ni < 4; ++ni) {
        float sc = scn[ni];
        #pragma unroll
        for (int mi = 0; mi < 4; ++mi)
            #pragma unroll
            for (int j = 0; j < 4; ++j) {
                int idx = mi * 4 + j;
                float d2v = fmaf(-2.0f, acc[mi][ni][j], sr[idx] + sc);
                float lo0 = fminf(st0[idx], d2v), hi0 = fmaxf(st0[idx], d2v);
                st0[idx] = lo0;
                float lo1 = fminf(st1[idx], hi0), hi1 = fmaxf(st1[idx], hi0);
                st1[idx] = lo1;
                st2[idx] = fminf(st2[idx], hi1);
                stx[idx] = fmaxf(stx[idx], d2v);
            }
    }
    #pragma unroll
    for (int s = 1; s < 16; s <<= 1) {
        #pragma unroll
        for (int i = 0; i < 16; ++i) {
            float b0 = __shfl_xor(st0[i], s);
            float b1 = __shfl_xor(st1[i], s);
            float b2 = __shfl_xor(st2[i], s);
            float bm = __shfl_xor(stx[i], s);
            float n0 = fminf(st0[i], b0);
            float n1 = fminf(fmaxf(st0[i], b0), fminf(st1[i], b1));
            float n2 = fminf(fminf(st2[i], b2),
                             fminf(fmaxf(st0[i], b1), fmaxf(st1[i], b0)));
            st0[i] = n0; st1[i] = n1; st2[i] = n2; stx[i] = fmaxf(stx[i], bm);
        }
    }
    if ((l & 15) == 0) {
        const int g = l >> 4;
        const int slot = 2 * J + wn;
        #pragma unroll
        for (int mi = 0; mi < 4; ++mi)
            #pragma unroll
            for (int j = 0; j < 4; ++j) {
                int row = r0 + wm * 64 + mi * 16 + g * 4 + j;
                part4[(size_t)slot * NROWS + row] =
                    make_float4(st0[mi * 4 + j], st1[mi * 4 + j],
                                st2[mi * 4 + j], stx[mi * 4 + j]);
            }
    }

    // ---- col-side fold: rows of J over this tile's 128 rows ----
    if (J > I) {
        float c0s[4], c1s[4], c2s[4], cxs[4];
        #pragma unroll
        for (int ni = 0; ni < 4; ++ni) {
            c0s[ni] = FLTMAX; c1s[ni] = FLTMAX; c2s[ni] = FLTMAX; cxs[ni] = 0.0f;
        }
        #pragma unroll
        for (int ni = 0; ni < 4; ++ni) {
            float sc = scn[ni];
            #pragma unroll
            for (int mi = 0; mi < 4; ++mi)
                #pragma unroll
                for (int j = 0; j < 4; ++j) {
                    float d2v = fmaf(-2.0f, acc[mi][ni][j], sr[mi * 4 + j] + sc);
                    float lo0 = fminf(c0s[ni], d2v), hi0 = fmaxf(c0s[ni], d2v);
                    c0s[ni] = lo0;
                    float lo1 = fminf(c1s[ni], hi0), hi1 = fmaxf(c1s[ni], hi0);
                    c1s[ni] = lo1;
                    c2s[ni] = fminf(c2s[ni], hi1);
                    cxs[ni] = fmaxf(cxs[ni], d2v);
                }
        }
        #pragma unroll
        for (int s = 16; s < 64; s <<= 1) {
            #pragma unroll
            for (int ni = 0; ni < 4; ++ni) {
                float b0 = __shfl_xor(c0s[ni], s);
                float b1 = __shfl_xor(c1s[ni], s);
                float b2 = __shfl_xor(c2s[ni], s);
                float bm = __shfl_xor(cxs[ni], s);
                float n0 = fminf(c0s[ni], b0);
                float n1 = fminf(fmaxf(c0s[ni], b0), fminf(c1s[ni], b1));
                float n2 = fminf(fminf(c2s[ni], b2),
                                 fminf(fmaxf(c0s[ni], b1), fmaxf(c1s[ni], b0)));
                c0s[ni] = n0; c1s[ni] = n1; c2s[ni] = n2; cxs[ni] = fmaxf(cxs[ni], bm);
            }
        }
        if (l < 16) {
            const int slot = 2 * I + wm;
            #pragma unroll
            for (int ni = 0; ni < 4; ++ni) {
                int colr = c0 + wn * 64 + ni * 16 + l;
                part4[(size_t)slot * NROWS + colr] =
                    make_float4(c0s[ni], c1s[ni], c2s[ni], cxs[ni]);
            }
        }
    }
}

// combine: fold all 64 slots per row (each written exactly once), sqrt + pred.
__global__ __launch_bounds__(256) void combine_kernel(const float4* __restrict__ part4,
                                                      float* __restrict__ out) {
    const int row = blockIdx.x * 256 + threadIdx.x;
    float m0 = FLTMAX, m1 = FLTMAX, m2 = FLTMAX, mx = 0.0f;
    for (int s = 0; s < 64; ++s) {
        float4 t = part4[(size_t)s * NROWS + row];
        float n0 = fminf(m0, t.x);
        float n1 = fminf(fmaxf(m0, t.x), fminf(m1, t.y));
        float n2 = fminf(fminf(m2, t.z), fminf(fmaxf(m0, t.y), fmaxf(m1, t.x)));
        m0 = n0; m1 = n1; m2 = n2; mx = fmaxf(mx, t.w);
    }
    float d1 = sqrtf(fmaxf(m1, 0.0f) + 1e-12f);
    float d2 = sqrtf(fmaxf(m2, 0.0f) + 1e-12f);
    float dm = sqrtf(fmaxf(mx, 0.0f) + 1e-12f);
    out[row] = (d1 / d2 < 0.6f) ? 2.0f / (1.0f + expf(d1))
                                : 2.0f / (1.0f + 2.0f * expf(dm));
}

// ============================================================================
// Path B (fallback, fp32 VALU) if ws too small
// ============================================================================

__global__ __launch_bounds__(256) void sq_kernel(const float* __restrict__ x,
                                                 float* __restrict__ sq) {
    int wid = threadIdx.x >> 6;
    int lane = threadIdx.x & 63;
    int row = blockIdx.x * 4 + wid;
    const float* f = x + (size_t)row * CDIM;
    float4 v0 = *(const float4*)(f + lane * 8);
    float4 v1 = *(const float4*)(f + lane * 8 + 4);
    float s = v0.x*v0.x + v0.y*v0.y + v0.z*v0.z + v0.w*v0.w
            + v1.x*v1.x + v1.y*v1.y + v1.z*v1.z + v1.w*v1.w;
    #pragma unroll
    for (int o = 32; o > 0; o >>= 1) s += __shfl_xor(s, o);
    if (lane == 0) sq[row] = s;
}

__global__ __launch_bounds__(256, 2) void fcm_kernel(const float* __restrict__ x,
                                                     const float* __restrict__ sq,
                                                     float* __restrict__ out) {
    __shared__ __align__(16) float a_s[32][36];
    __shared__ __align__(16) float b_s[32][260];
    const int tid = threadIdx.x;
    const int ty = tid >> 6;
    const int tx = tid & 63;
    const int brow = blockIdx.x * 32;
    const int batch = brow >> 12;
    const int irow = brow & (NPTS - 1);
    const float* f = x + (size_t)batch * NPTS * CDIM;
    const float* sqb = sq + batch * NPTS;

    float srr[8];
    #pragma unroll
    for (int r = 0; r < 8; ++r) srr[r] = sqb[irow + ty * 8 + r];
    float m0[8], m1[8], m2[8], mx[8];
    #pragma unroll
    for (int r = 0; r < 8; ++r) {
        m0[r] = FLTMAX; m1[r] = FLTMAX; m2[r] = FLTMAX; mx[r] = 0.0f;
    }
    for (int ct = 0; ct < NPTS / 256; ++ct) {
        const int cbase = ct * 256;
        float acc[8][4];
        #pragma unroll
        for (int r = 0; r < 8; ++r)
            #pragma unroll
            for (int q = 0; q < 4; ++q) acc[r][q] = 0.0f;
        for (int kc = 0; kc < CDIM; kc += 32) {
            {
                int row = tid >> 3, l8 = tid & 7;
                float4 v = *(const float4*)(f + (size_t)(irow + row) * CDIM + kc + l8 * 4);
                a_s[l8 * 4 + 0][row] = v.x; a_s[l8 * 4 + 1][row] = v.y;
                a_s[l8 * 4 + 2][row] = v.z; a_s[l8 * 4 + 3][row] = v.w;
            }
            {
                int colb = tid >> 2, l4 = tid & 3;
                #pragma unroll
                for (int it = 0; it < 4; ++it) {
                    int col = colb + 64 * it;
                    const float* p = f + (size_t)(cbase + col) * CDIM + kc + l4 * 8;
                    float4 v0 = *(const float4*)p;
                    float4 v1 = *(const float4*)(p + 4);
                    b_s[l4 * 8 + 0][col] = v0.x; b_s[l4 * 8 + 1][col] = v0.y;
                    b_s[l4 * 8 + 2][col] = v0.z; b_s[l4 * 8 + 3][col] = v0.w;
                    b_s[l4 * 8 + 4][col] = v1.x; b_s[l4 * 8 + 5][col] = v1.y;
                    b_s[l4 * 8 + 6][col] = v1.z; b_s[l4 * 8 + 7][col] = v1.w;
                }
            }
            __syncthreads();
            #pragma unroll
            for (int k = 0; k < 32; ++k) {
                float a0[8], b0[4];
                *(float4*)&a0[0] = *(const float4*)&a_s[k][ty * 8];
                *(float4*)&a0[4] = *(const float4*)&a_s[k][ty * 8 + 4];
                *(float4*)&b0[0] = *(const float4*)&b_s[k][tx * 4];
                #pragma unroll
                for (int r = 0; r < 8; ++r)
                    #pragma unroll
                    for (int q = 0; q < 4; ++q)
                        acc[r][q] = fmaf(a0[r], b0[q], acc[r][q]);
            }
            __syncthreads();
        }
        #pragma unroll
        for (int q = 0; q < 4; ++q) {
            float sc = sqb[cbase + tx * 4 + q];
            #pragma unroll
            for (int r = 0; r < 8; ++r) {
                float d2v = fmaf(-2.0f, acc[r][q], srr[r] + sc);
                d2v = fmaxf(d2v, 0.0f);
                float d = sqrtf(d2v + 1e-12f);
                float lo = fminf(m0[r], d), hi = fmaxf(m0[r], d);
                m0[r] = lo;
                float lo1 = fminf(m1[r], hi), hi1 = fmaxf(m1[r], hi);
                m1[r] = lo1;
                m2[r] = fminf(m2[r], hi1);
                mx[r] = fmaxf(mx[r], d);
            }
        }
    }
    #pragma unroll
    for (int s = 1; s < 64; s <<= 1) {
        #pragma unroll
        for (int r = 0; r < 8; ++r) {
            float b0v = __shfl_xor(m0[r], s);
            float b1v = __shfl_xor(m1[r], s);
            float b2v = __shfl_xor(m2[r], s);
            float bmv = __shfl_xor(mx[r], s);
            float n0 = fminf(m0[r], b0v);
            float n1 = fminf(fmaxf(m0[r], b0v), fminf(m1[r], b1v));
            float n2 = fminf(fminf(m2[r], b2v),
                             fminf(fmaxf(m0[r], b1v), fmaxf(m1[r], b0v)));
            m0[r] = n0; m1[r] = n1; m2[r] = n2; mx[r] = fmaxf(mx[r], bmv);
        }
    }
    if (tx == 0) {
        #pragma unroll
        for (int r = 0; r < 8; ++r) {
            int grow = brow + ty * 8 + r;
            float d1 = m1[r], d2nd = m2[r], dmaxv = mx[r];
            float pred = (d1 / d2nd < 0.6f) ? 2.0f / (1.0f + expf(d1))
                                            : 2.0f / (1.0f + 2.0f * expf(dmaxv));
            out[grow] = pred;
        }
    }
}

extern "C" void kernel_launch(void* const* d_in, const int* in_sizes, int n_in,
                              void* d_out, int out_size, void* d_ws, size_t ws_size,
                              hipStream_t stream) {
    const float* x = (const float*)d_in[0];
    float* out = (float*)d_out;

    const size_t plane = (size_t)NROWS * CDIM * sizeof(half_t);      // 16 MB
    const size_t partb = (size_t)64 * NROWS * sizeof(float4);        // 16 MB
    const size_t need = plane + NROWS * sizeof(float) + partb;

    if (ws_size >= need) {
        half_t* hi = (half_t*)d_ws;
        float* sq = (float*)((char*)d_ws + plane);
        float4* part4 = (float4*)((char*)d_ws + plane + NROWS * sizeof(float));
        prep_kernel<<<dim3(NROWS / 4), dim3(256), 0, stream>>>(x, hi, sq);
        fcm_sym<<<dim3(4 * NTILES), dim3(256), 0, stream>>>(hi, sq, part4);
        combine_kernel<<<dim3(NROWS / 256), dim3(256), 0, stream>>>(part4, out);
    } else {
        float* sqw = (float*)d_ws;
        sq_kernel<<<dim3(4096), dim3(256), 0, stream>>>(x, sqw);
        fcm_kernel<<<dim3(512), dim3(256), 0, stream>>>(x, sqw, out);
    }
}

// Round 7
// 96.675 us; speedup vs baseline: 1.2534x; 1.0512x over previous
//
#include <hip/hip_runtime.h>
#include <math.h>

#define NPTS 4096
#define CDIM 512
#define NROWS 16384
#define NTILES 528   // 32*33/2 tri-tiles of 128 per batch
#define FLTMAX 3.402823466e+38f

typedef _Float16 half_t;
typedef _Float16 half8 __attribute__((ext_vector_type(8)));
typedef float f32x4 __attribute__((ext_vector_type(4)));

__device__ inline void gl_lds16(const void* g, void* l) {
    __builtin_amdgcn_global_load_lds(
        (const __attribute__((address_space(1))) uint32_t*)g,
        (__attribute__((address_space(3))) uint32_t*)l, 16, 0, 0);
}

__device__ __forceinline__ int tri_start(int i) { return 32 * i - (i * (i - 1)) / 2; }

// ============================================================================
// Path A: prep -> fcm_sym (128x128 tri tiles, XCD-chunked tile order) -> combine
// Global f16 image: row stride 1024 B; 8 Kblocks of 64 ch (128 B); 16B slot s
// of each Kblock stored at position s^(row&7) (pre-baked LDS swizzle).
// ============================================================================

__global__ __launch_bounds__(256) void prep_kernel(const float* __restrict__ x,
                                                   half_t* __restrict__ hi,
                                                   float* __restrict__ sq) {
    const int wv = threadIdx.x >> 6, l = threadIdx.x & 63;
    const int row = blockIdx.x * 4 + wv;
    const float* f = x + (size_t)row * CDIM;
    float4 v0 = *(const float4*)(f + l * 8);
    float4 v1 = *(const float4*)(f + l * 8 + 4);
    float xs[8] = {v0.x, v0.y, v0.z, v0.w, v1.x, v1.y, v1.z, v1.w};
    half8 h;
    float s = 0.0f;
    #pragma unroll
    for (int i = 0; i < 8; ++i) {
        float v = xs[i];
        s = fmaf(v, v, s);
        h[i] = (half_t)v;
    }
    #pragma unroll
    for (int o = 32; o > 0; o >>= 1) s += __shfl_xor(s, o);
    const int kb = l >> 3;
    const int pos = (l & 7) ^ (row & 7);
    *(half8*)(hi + (size_t)row * CDIM + kb * 64 + pos * 8) = h;
    if (l == 0) sq[row] = s;
}

// One block per triangular tile (I,J), J>=I, per batch. 128x128 tile, 4 waves
// (2x2, 64x64 each), BK=64, double-buffered LDS via global_load_lds.
// XCD-chunked block order: each XCD gets a contiguous run of the (I,J)-sorted
// triangle so co-resident blocks share A-rows (and a compact J window) in its
// private L2. 2112 blocks = 8 XCDs x 264, bijective.
// Epilogue: row-side fold -> slot 2J+wn; col-side fold (skip if I==J)
//   -> slot 2I+wm. part layout: [slot][row] float4 (m0,m1,m2,max), d^2 domain.
__global__ __launch_bounds__(256, 2) void fcm_sym(const half_t* __restrict__ hi,
                                                  const float* __restrict__ sq,
                                                  float4* __restrict__ part4) {
    __shared__ __align__(16) char smem[2][2][16384];
    const int tid = threadIdx.x, wv = tid >> 6, l = tid & 63;
    const int wm = wv >> 1, wn = wv & 1;
    const int wg = blockIdx.x;
    const int tl = (wg & 7) * 264 + (wg >> 3);        // XCD-chunked, bijective
    const int batch = tl / NTILES;
    const int t = tl - batch * NTILES;
    int I = (int)((65.0f - sqrtf(4225.0f - 8.0f * (float)t)) * 0.5f);
    while (tri_start(I + 1) <= t) ++I;
    while (tri_start(I) > t) --I;
    const int J = I + (t - tri_start(I));
    const int r0 = (batch << 12) + I * 128;
    const int c0 = (batch << 12) + J * 128;
    const char* base = (const char*)hi;

    float sr[16];
    #pragma unroll
    for (int mi = 0; mi < 4; ++mi)
        #pragma unroll
        for (int j = 0; j < 4; ++j)
            sr[mi * 4 + j] = sq[r0 + wm * 64 + mi * 16 + (l >> 4) * 4 + j];
    float scn[4];
    #pragma unroll
    for (int ni = 0; ni < 4; ++ni)
        scn[ni] = sq[c0 + wn * 64 + ni * 16 + (l & 15)];

    // fragment byte offsets within A/B LDS buffers (constant per thread)
    int aoff[4][2], boff[4][2];
    #pragma unroll
    for (int q = 0; q < 4; ++q)
        #pragma unroll
        for (int kc = 0; kc < 2; ++kc) {
            int rowa = wm * 64 + q * 16 + (l & 15);
            aoff[q][kc] = rowa * 128 + ((((l >> 4) + kc * 4) ^ (rowa & 7)) * 16);
            int rowb = wn * 64 + q * 16 + (l & 15);
            boff[q][kc] = rowb * 128 + ((((l >> 4) + kc * 4) ^ (rowb & 7)) * 16);
        }

    int srow[4], sin[4];
    #pragma unroll
    for (int i = 0; i < 4; ++i) {
        int dl = i * 4096 + wv * 1024 + l * 16;
        srow[i] = dl >> 7;
        sin[i] = dl & 127;
    }

#define STAGE(buf, ksv) do {                                                   \
        _Pragma("unroll")                                                      \
        for (int i_ = 0; i_ < 4; ++i_) {                                       \
            const int db_ = i_ * 4096 + wv * 1024;                             \
            gl_lds16(base + (size_t)(r0 + srow[i_]) * 1024 + (ksv) * 128 + sin[i_], \
                     &smem[buf][0][db_]);                                      \
            gl_lds16(base + (size_t)(c0 + srow[i_]) * 1024 + (ksv) * 128 + sin[i_], \
                     &smem[buf][1][db_]);                                      \
        } } while (0)

    f32x4 acc[4][4];
    #pragma unroll
    for (int mi = 0; mi < 4; ++mi)
        #pragma unroll
        for (int ni = 0; ni < 4; ++ni)
            #pragma unroll
            for (int j = 0; j < 4; ++j) acc[mi][ni][j] = 0.0f;

    STAGE(0, 0);
    __syncthreads();
    #pragma unroll
    for (int ks = 0; ks < 8; ++ks) {
        const int cur = ks & 1;
        if (ks < 7) STAGE(cur ^ 1, ks + 1);
        #pragma unroll
        for (int kc = 0; kc < 2; ++kc) {
            half8 af[4], bf[4];
            #pragma unroll
            for (int q = 0; q < 4; ++q) {
                af[q] = *(const half8*)&smem[cur][0][aoff[q][kc]];
                bf[q] = *(const half8*)&smem[cur][1][boff[q][kc]];
            }
            #pragma unroll
            for (int mi = 0; mi < 4; ++mi)
                #pragma unroll
                for (int ni = 0; ni < 4; ++ni)
                    acc[mi][ni] = __builtin_amdgcn_mfma_f32_16x16x32_f16(
                        af[mi], bf[ni], acc[mi][ni], 0, 0, 0);
        }
        __syncthreads();
    }
#undef STAGE

    // ---- row-side fold: rows of block I over this tile's 128 cols ----
    float st0[16], st1[16], st2[16], stx[16];
    #pragma unroll
    for (int i = 0; i < 16; ++i) {
        st0[i] = FLTMAX; st1[i] = FLTMAX; st2[i] = FLTMAX; stx[i] = 0.0f;
    }
    #pragma unroll
    for (int ni = 0; ni < 4; ++ni) {
        float sc = scn[ni];
        #pragma unroll
        for (int mi = 0; mi < 4; ++mi)
            #pragma unroll
            for (int j = 0; j < 4; ++j) {
                int idx = mi * 4 + j;
                float d2v = fmaf(-2.0f, acc[mi][ni][j], sr[idx] + sc);
                float lo0 = fminf(st0[idx], d2v), hi0 = fmaxf(st0[idx], d2v);
                st0[idx] = lo0;
                float lo1 = fminf(st1[idx], hi0), hi1 = fmaxf(st1[idx], hi0);
                st1[idx] = lo1;
                st2[idx] = fminf(st2[idx], hi1);
                stx[idx] = fmaxf(stx[idx], d2v);
            }
    }
    #pragma unroll
    for (int s = 1; s < 16; s <<= 1) {
        #pragma unroll
        for (int i = 0; i < 16; ++i) {
            float b0 = __shfl_xor(st0[i], s);
            float b1 = __shfl_xor(st1[i], s);
            float b2 = __shfl_xor(st2[i], s);
            float bm = __shfl_xor(stx[i], s);
            float n0 = fminf(st0[i], b0);
            float n1 = fminf(fmaxf(st0[i], b0), fminf(st1[i], b1));
            float n2 = fminf(fminf(st2[i], b2),
                             fminf(fmaxf(st0[i], b1), fmaxf(st1[i], b0)));
            st0[i] = n0; st1[i] = n1; st2[i] = n2; stx[i] = fmaxf(stx[i], bm);
        }
    }
    if ((l & 15) == 0) {
        const int g = l >> 4;
        const int slot = 2 * J + wn;
        #pragma unroll
        for (int mi = 0; mi < 4; ++mi)
            #pragma unroll
            for (int j = 0; j < 4; ++j) {
                int row = r0 + wm * 64 + mi * 16 + g * 4 + j;
                part4[(size_t)slot * NROWS + row] =
                    make_float4(st0[mi * 4 + j], st1[mi * 4 + j],
                                st2[mi * 4 + j], stx[mi * 4 + j]);
            }
    }

    // ---- col-side fold: rows of block J over this tile's 128 rows ----
    if (J > I) {
        float c0s[4], c1s[4], c2s[4], cxs[4];
        #pragma unroll
        for (int ni = 0; ni < 4; ++ni) {
            c0s[ni] = FLTMAX; c1s[ni] = FLTMAX; c2s[ni] = FLTMAX; cxs[ni] = 0.0f;
        }
        #pragma unroll
        for (int ni = 0; ni < 4; ++ni) {
            float sc = scn[ni];
            #pragma unroll
            for (int mi = 0; mi < 4; ++mi)
                #pragma unroll
                for (int j = 0; j < 4; ++j) {
                    float d2v = fmaf(-2.0f, acc[mi][ni][j], sr[mi * 4 + j] + sc);
                    float lo0 = fminf(c0s[ni], d2v), hi0 = fmaxf(c0s[ni], d2v);
                    c0s[ni] = lo0;
                    float lo1 = fminf(c1s[ni], hi0), hi1 = fmaxf(c1s[ni], hi0);
                    c1s[ni] = lo1;
                    c2s[ni] = fminf(c2s[ni], hi1);
                    cxs[ni] = fmaxf(cxs[ni], d2v);
                }
        }
        #pragma unroll
        for (int s = 16; s < 64; s <<= 1) {
            #pragma unroll
            for (int ni = 0; ni < 4; ++ni) {
                float b0 = __shfl_xor(c0s[ni], s);
                float b1 = __shfl_xor(c1s[ni], s);
                float b2 = __shfl_xor(c2s[ni], s);
                float bm = __shfl_xor(cxs[ni], s);
                float n0 = fminf(c0s[ni], b0);
                float n1 = fminf(fmaxf(c0s[ni], b0), fminf(c1s[ni], b1));
                float n2 = fminf(fminf(c2s[ni], b2),
                                 fminf(fmaxf(c0s[ni], b1), fmaxf(c1s[ni], b0)));
                c0s[ni] = n0; c1s[ni] = n1; c2s[ni] = n2; cxs[ni] = fmaxf(cxs[ni], bm);
            }
        }
        if (l < 16) {
            const int slot = 2 * I + wm;
            #pragma unroll
            for (int ni = 0; ni < 4; ++ni) {
                int colr = c0 + wn * 64 + ni * 16 + l;
                part4[(size_t)slot * NROWS + colr] =
                    make_float4(c0s[ni], c1s[ni], c2s[ni], cxs[ni]);
            }
        }
    }
}

// combine: fold all 64 slots per row (each written exactly once), sqrt + pred.
__global__ __launch_bounds__(256) void combine_kernel(const float4* __restrict__ part4,
                                                      float* __restrict__ out) {
    const int row = blockIdx.x * 256 + threadIdx.x;
    float m0 = FLTMAX, m1 = FLTMAX, m2 = FLTMAX, mx = 0.0f;
    for (int s = 0; s < 64; ++s) {
        float4 t = part4[(size_t)s * NROWS + row];
        float n0 = fminf(m0, t.x);
        float n1 = fminf(fmaxf(m0, t.x), fminf(m1, t.y));
        float n2 = fminf(fminf(m2, t.z), fminf(fmaxf(m0, t.y), fmaxf(m1, t.x)));
        m0 = n0; m1 = n1; m2 = n2; mx = fmaxf(mx, t.w);
    }
    float d1 = sqrtf(fmaxf(m1, 0.0f) + 1e-12f);
    float d2 = sqrtf(fmaxf(m2, 0.0f) + 1e-12f);
    float dm = sqrtf(fmaxf(mx, 0.0f) + 1e-12f);
    out[row] = (d1 / d2 < 0.6f) ? 2.0f / (1.0f + expf(d1))
                                : 2.0f / (1.0f + 2.0f * expf(dm));
}

// ============================================================================
// Path B (fallback, fp32 VALU) if ws too small
// ============================================================================

__global__ __launch_bounds__(256) void sq_kernel(const float* __restrict__ x,
                                                 float* __restrict__ sq) {
    int wid = threadIdx.x >> 6;
    int lane = threadIdx.x & 63;
    int row = blockIdx.x * 4 + wid;
    const float* f = x + (size_t)row * CDIM;
    float4 v0 = *(const float4*)(f + lane * 8);
    float4 v1 = *(const float4*)(f + lane * 8 + 4);
    float s = v0.x*v0.x + v0.y*v0.y + v0.z*v0.z + v0.w*v0.w
            + v1.x*v1.x + v1.y*v1.y + v1.z*v1.z + v1.w*v1.w;
    #pragma unroll
    for (int o = 32; o > 0; o >>= 1) s += __shfl_xor(s, o);
    if (lane == 0) sq[row] = s;
}

__global__ __launch_bounds__(256, 2) void fcm_kernel(const float* __restrict__ x,
                                                     const float* __restrict__ sq,
                                                     float* __restrict__ out) {
    __shared__ __align__(16) float a_s[32][36];
    __shared__ __align__(16) float b_s[32][260];
    const int tid = threadIdx.x;
    const int ty = tid >> 6;
    const int tx = tid & 63;
    const int brow = blockIdx.x * 32;
    const int batch = brow >> 12;
    const int irow = brow & (NPTS - 1);
    const float* f = x + (size_t)batch * NPTS * CDIM;
    const float* sqb = sq + batch * NPTS;

    float srr[8];
    #pragma unroll
    for (int r = 0; r < 8; ++r) srr[r] = sqb[irow + ty * 8 + r];
    float m0[8], m1[8], m2[8], mx[8];
    #pragma unroll
    for (int r = 0; r < 8; ++r) {
        m0[r] = FLTMAX; m1[r] = FLTMAX; m2[r] = FLTMAX; mx[r] = 0.0f;
    }
    for (int ct = 0; ct < NPTS / 256; ++ct) {
        const int cbase = ct * 256;
        float acc[8][4];
        #pragma unroll
        for (int r = 0; r < 8; ++r)
            #pragma unroll
            for (int q = 0; q < 4; ++q) acc[r][q] = 0.0f;
        for (int kc = 0; kc < CDIM; kc += 32) {
            {
                int row = tid >> 3, l8 = tid & 7;
                float4 v = *(const float4*)(f + (size_t)(irow + row) * CDIM + kc + l8 * 4);
                a_s[l8 * 4 + 0][row] = v.x; a_s[l8 * 4 + 1][row] = v.y;
                a_s[l8 * 4 + 2][row] = v.z; a_s[l8 * 4 + 3][row] = v.w;
            }
            {
                int colb = tid >> 2, l4 = tid & 3;
                #pragma unroll
                for (int it = 0; it < 4; ++it) {
                    int col = colb + 64 * it;
                    const float* p = f + (size_t)(cbase + col) * CDIM + kc + l4 * 8;
                    float4 v0 = *(const float4*)p;
                    float4 v1 = *(const float4*)(p + 4);
                    b_s[l4 * 8 + 0][col] = v0.x; b_s[l4 * 8 + 1][col] = v0.y;
                    b_s[l4 * 8 + 2][col] = v0.z; b_s[l4 * 8 + 3][col] = v0.w;
                    b_s[l4 * 8 + 4][col] = v1.x; b_s[l4 * 8 + 5][col] = v1.y;
                    b_s[l4 * 8 + 6][col] = v1.z; b_s[l4 * 8 + 7][col] = v1.w;
                }
            }
            __syncthreads();
            #pragma unroll
            for (int k = 0; k < 32; ++k) {
                float a0[8], b0[4];
                *(float4*)&a0[0] = *(const float4*)&a_s[k][ty * 8];
                *(float4*)&a0[4] = *(const float4*)&a_s[k][ty * 8 + 4];
                *(float4*)&b0[0] = *(const float4*)&b_s[k][tx * 4];
                #pragma unroll
                for (int r = 0; r < 8; ++r)
                    #pragma unroll
                    for (int q = 0; q < 4; ++q)
                        acc[r][q] = fmaf(a0[r], b0[q], acc[r][q]);
            }
            __syncthreads();
        }
        #pragma unroll
        for (int q = 0; q < 4; ++q) {
            float sc = sqb[cbase + tx * 4 + q];
            #pragma unroll
            for (int r = 0; r < 8; ++r) {
                float d2v = fmaf(-2.0f, acc[r][q], srr[r] + sc);
                d2v = fmaxf(d2v, 0.0f);
                float d = sqrtf(d2v + 1e-12f);
                float lo = fminf(m0[r], d), hi = fmaxf(m0[r], d);
                m0[r] = lo;
                float lo1 = fminf(m1[r], hi), hi1 = fmaxf(m1[r], hi);
                m1[r] = lo1;
                m2[r] = fminf(m2[r], hi1);
                mx[r] = fmaxf(mx[r], d);
            }
        }
    }
    #pragma unroll
    for (int s = 1; s < 64; s <<= 1) {
        #pragma unroll
        for (int r = 0; r < 8; ++r) {
            float b0v = __shfl_xor(m0[r], s);
            float b1v = __shfl_xor(m1[r], s);
            float b2v = __shfl_xor(m2[r], s);
            float bmv = __shfl_xor(mx[r], s);
            float n0 = fminf(m0[r], b0v);
            float n1 = fminf(fmaxf(m0[r], b0v), fminf(m1[r], b1v));
            float n2 = fminf(fminf(m2[r], b2v),
                             fminf(fmaxf(m0[r], b1v), fmaxf(m1[r], b0v)));
            m0[r] = n0; m1[r] = n1; m2[r] = n2; mx[r] = fmaxf(mx[r], bmv);
        }
    }
    if (tx == 0) {
        #pragma unroll
        for (int r = 0; r < 8; ++r) {
            int grow = brow + ty * 8 + r;
            float d1 = m1[r], d2nd = m2[r], dmaxv = mx[r];
            float pred = (d1 / d2nd < 0.6f) ? 2.0f / (1.0f + expf(d1))
                                            : 2.0f / (1.0f + 2.0f * expf(dmaxv));
            out[grow] = pred;
        }
    }
}

extern "C" void kernel_launch(void* const* d_in, const int* in_sizes, int n_in,
                              void* d_out, int out_size, void* d_ws, size_t ws_size,
                              hipStream_t stream) {
    const float* x = (const float*)d_in[0];
    float* out = (float*)d_out;

    const size_t plane = (size_t)NROWS * CDIM * sizeof(half_t);      // 16 MB
    const size_t partb = (size_t)64 * NROWS * sizeof(float4);        // 16 MB
    const size_t need = plane + NROWS * sizeof(float) + partb;

    if (ws_size >= need) {
        half_t* hi = (half_t*)d_ws;
        float* sq = (float*)((char*)d_ws + plane);
        float4* part4 = (float4*)((char*)d_ws + plane + NROWS * sizeof(float));
        prep_kernel<<<dim3(NROWS / 4), dim3(256), 0, stream>>>(x, hi, sq);
        fcm_sym<<<dim3(4 * NTILES), dim3(256), 0, stream>>>(hi, sq, part4);
        combine_kernel<<<dim3(NROWS / 256), dim3(256), 0, stream>>>(part4, out);
    } else {
        float* sqw = (float*)d_ws;
        sq_kernel<<<dim3(4096), dim3(256), 0, stream>>>(x, sqw);
        fcm_kernel<<<dim3(512), dim3(256), 0, stream>>>(x, sqw, out);
    }
}